// Round 3
// baseline (482.779 us; speedup 1.0000x reference)
//
#include <hip/hip_runtime.h>
#include <stdint.h>

typedef _Float16 f16;
typedef __attribute__((ext_vector_type(8))) _Float16 f16x8;
typedef __attribute__((ext_vector_type(4))) _Float16 f16x4;
typedef __attribute__((ext_vector_type(4))) float    f32x4;

constexpr int BB   = 4;
constexpr int NN   = 256;
constexpr int CIN  = 256;
constexpr int CHID = 128;
constexpr int HH   = 256;
constexpr int WW   = 256;
constexpr int NPIX = HH * WW;
constexpr int SS   = 256;

// Output layout (fp32 elements, concatenated in return order)
constexpr int OUT_MATCH  = 0;      // [B,N,2] = 2048
constexpr int OUT_VALID  = 2048;   // [B,N]   = 1024
constexpr int OUT_CANDT  = 3072;   // [B,S,3] = 3072
constexpr int OUT_SCORES = 6144;   // [B,S]   = 1024

// A = K_sat * R_sat^T, ub = A*(R_l2w*(Kinv*[u,v,1]*d) + t_init - t_sat)
static __device__ __forceinline__ void compute_geom(
    const float* Kl, const float* Rl, const float* ti,
    const float* Ks, const float* Rs, const float* ts,
    float u, float v, float d, float* A, float* ub)
{
  float a = Kl[0], bq = Kl[1], c = Kl[2];
  float dq = Kl[3], e = Kl[4], f = Kl[5];
  float g = Kl[6], h = Kl[7], i = Kl[8];
  float cof00 =  (e*i - f*h), cof01 = -(dq*i - f*g), cof02 =  (dq*h - e*g);
  float cof10 = -(bq*i - c*h), cof11 =  (a*i - c*g), cof12 = -(a*h - bq*g);
  float cof20 =  (bq*f - c*e), cof21 = -(a*f - c*dq), cof22 =  (a*e - bq*dq);
  float det = a*cof00 + bq*cof01 + c*cof02;
  float inv = 1.0f / det;
  float k00 = cof00*inv, k01 = cof10*inv, k02 = cof20*inv;
  float k10 = cof01*inv, k11 = cof11*inv, k12 = cof21*inv;
  float k20 = cof02*inv, k21 = cof12*inv, k22 = cof22*inv;
  float cx = (k00*u + k01*v + k02) * d;
  float cy = (k10*u + k11*v + k12) * d;
  float cz = (k20*u + k21*v + k22) * d;
  float w0 = Rl[0]*cx + Rl[1]*cy + Rl[2]*cz + ti[0] - ts[0];
  float w1 = Rl[3]*cx + Rl[4]*cy + Rl[5]*cz + ti[1] - ts[1];
  float w2 = Rl[6]*cx + Rl[7]*cy + Rl[8]*cz + ti[2] - ts[2];
  #pragma unroll
  for (int r = 0; r < 3; ++r)
    #pragma unroll
    for (int cJ = 0; cJ < 3; ++cJ)
      A[r*3 + cJ] = Ks[r*3+0]*Rs[cJ*3+0] + Ks[r*3+1]*Rs[cJ*3+1] + Ks[r*3+2]*Rs[cJ*3+2];
  ub[0] = A[0]*w0 + A[1]*w1 + A[2]*w2;
  ub[1] = A[3]*w0 + A[4]*w1 + A[5]*w2;
  ub[2] = A[6]*w0 + A[7]*w1 + A[8]*w2;
}

static __device__ __forceinline__ void proj(const float* A, const float* ub,
                                            float oxr, float oyr,
                                            float& cx, float& cy)
{
  float u0 = ub[0] + oxr*A[0] + oyr*A[1];
  float u1 = ub[1] + oxr*A[3] + oyr*A[4];
  float u2 = ub[2] + oxr*A[6] + oyr*A[7];
  cx = u0 / u2;
  cy = u1 / u2;
}

// ============================ Path A (ws >= ~34MiB) ============================

// Split W_sat [128][256] fp32 into hi/lo fp16 (error-compensated MFMA operands).
__global__ __launch_bounds__(256) void kPrep(const float* __restrict__ Wsat,
                                             f16* __restrict__ Wh,
                                             f16* __restrict__ Wl,
                                             float* __restrict__ logits)
{
  int idx = blockIdx.x * 256 + threadIdx.x;      // 0..32767
  float v = Wsat[idx];
  f16 hv = (f16)v;
  Wh[idx] = hv;
  Wl[idx] = (f16)(v - (float)hv);
  if (idx < BB*SS) logits[idx] = 0.0f;
}

__global__ __launch_bounds__(128) void kNode(const float* __restrict__ feats,
                                             const float* __restrict__ Wn,
                                             const float* __restrict__ bn,
                                             float* __restrict__ nf)
{
  int bnI = blockIdx.x;
  int h = threadIdx.x;
  __shared__ float frow[CIN];
  __shared__ float red[2];
  frow[h]       = feats[(size_t)bnI*CIN + h];
  frow[h + 128] = feats[(size_t)bnI*CIN + h + 128];
  __syncthreads();
  float acc = bn[h];
  #pragma unroll 8
  for (int c = 0; c < CIN; ++c) acc += frow[c] * Wn[c*CHID + h];
  float s = acc * acc;
  #pragma unroll
  for (int off = 32; off; off >>= 1) s += __shfl_down(s, off);
  if ((h & 63) == 0) red[h >> 6] = s;
  __syncthreads();
  float inv = 1.0f / fmaxf(sqrtf(red[0] + red[1]), 1e-12f);
  nf[(size_t)bnI*CHID + h] = acc * inv;
}

// sf = W_sat @ featmap + b_sat via split-f16 MFMA (3-term: WhFh + WhFl + WlFh),
// channel-normalized, fp16 [B,HW,128].
// v2: K split into 2 phases of 128 (LDS 36KB -> 3 blocks/CU), W frags reloaded
// per phase (64 VGPR not 128), phase-1 global loads issued before phase-0
// compute (T14 async-stage split). Accumulation order identical to v1.
constexpr int P2 = 136;   // fp16 per LDS row: 128 + 8 pad (2-way read conflict only)

__global__ __launch_bounds__(256, 3) void kSatM(
    const float* __restrict__ sat, const f16* __restrict__ Wh,
    const f16* __restrict__ Wl, const float* __restrict__ bsat,
    f16* __restrict__ sfn)
{
  const int b  = blockIdx.y;
  const int p0 = blockIdx.x * 64;
  __shared__ f16 FhS[64 * P2];        // [pixel][channel 0..127] hi
  __shared__ f16 FlS[64 * P2];        // [pixel][channel 0..127] lo
  __shared__ float nrm[4][64];        // per-wave per-pixel |sf|^2 partials

  const int tid = threadIdx.x;
  const int w   = tid >> 6;
  const int l   = tid & 63;
  const int q   = tid & 15;           // pixel quad (pixels q*4..q*4+3)
  const int cg  = tid >> 4;           // channel group (4 channels)
  const float* Fb = sat + (size_t)b * CIN * NPIX + p0;

  const int orow = w*32 + (l & 15);
  const int koff = (l >> 4) * 8;

  // ---- accumulators init = bias (added pre-normalization, as in reference)
  f32x4 acc[4][2];
  {
    int ob = w*32 + (l >> 4) * 4;
    f32x4 b0 = *(const f32x4*)(bsat + ob);
    f32x4 b1 = *(const f32x4*)(bsat + ob + 16);
    #pragma unroll
    for (int pt = 0; pt < 4; ++pt) { acc[pt][0] = b0; acc[pt][1] = b1; }
  }

  float4 r[8];
  // ---- phase-0 loads (channels 0..127): 2 passes x 4 channel rows
  #pragma unroll
  for (int p = 0; p < 2; ++p)
    #pragma unroll
    for (int j = 0; j < 4; ++j)
      r[p*4 + j] = *(const float4*)(Fb + (size_t)(p*64 + cg*4 + j) * NPIX + q*4);

  // ---- convert + LDS write (phase 0)
  #pragma unroll
  for (int p = 0; p < 2; ++p) {
    int cbase = p*64 + cg*4;
    #pragma unroll
    for (int i2 = 0; i2 < 4; ++i2) {
      f16x4 hv, lv;
      #pragma unroll
      for (int j = 0; j < 4; ++j) {
        float v = (i2 == 0) ? r[p*4+j].x : (i2 == 1) ? r[p*4+j].y
                : (i2 == 2) ? r[p*4+j].z : r[p*4+j].w;
        f16 hq = (f16)v;
        hv[j] = hq;
        lv[j] = (f16)(v - (float)hq);
      }
      *(f16x4*)(FhS + (q*4 + i2)*P2 + cbase) = hv;
      *(f16x4*)(FlS + (q*4 + i2)*P2 + cbase) = lv;
    }
  }
  __syncthreads();

  // ---- issue phase-1 global loads EARLY (latency hides under phase-0 MFMAs)
  #pragma unroll
  for (int p = 0; p < 2; ++p)
    #pragma unroll
    for (int j = 0; j < 4; ++j)
      r[p*4 + j] = *(const float4*)(Fb + (size_t)(128 + p*64 + cg*4 + j) * NPIX + q*4);

  // ---- W fragments for phase 0 (k 0..127) from L2
  f16x8 wah[2][4], wal[2][4];
  #pragma unroll
  for (int ot = 0; ot < 2; ++ot) {
    const f16* bh  = Wh + (size_t)(orow + ot*16) * CIN + koff;
    const f16* blp = Wl + (size_t)(orow + ot*16) * CIN + koff;
    #pragma unroll
    for (int ks = 0; ks < 4; ++ks) {
      wah[ot][ks] = *(const f16x8*)(bh  + ks*32);
      wal[ot][ks] = *(const f16x8*)(blp + ks*32);
    }
  }

  // ---- compute phase 0: 4 ks x 4 pt x 2 ot x 3 terms = 96 MFMAs
  #pragma unroll
  for (int ks = 0; ks < 4; ++ks) {
    #pragma unroll
    for (int pt = 0; pt < 4; ++pt) {
      int rofs = (pt*16 + (l & 15)) * P2 + ks*32 + koff;
      f16x8 bh = *(const f16x8*)(FhS + rofs);
      f16x8 bl = *(const f16x8*)(FlS + rofs);
      #pragma unroll
      for (int ot = 0; ot < 2; ++ot) {
        acc[pt][ot] = __builtin_amdgcn_mfma_f32_16x16x32_f16(wah[ot][ks], bh, acc[pt][ot], 0, 0, 0);
        acc[pt][ot] = __builtin_amdgcn_mfma_f32_16x16x32_f16(wah[ot][ks], bl, acc[pt][ot], 0, 0, 0);
        acc[pt][ot] = __builtin_amdgcn_mfma_f32_16x16x32_f16(wal[ot][ks], bh, acc[pt][ot], 0, 0, 0);
      }
    }
  }
  __syncthreads();   // all waves done reading LDS phase 0

  // ---- convert + LDS write (phase 1, from prefetched regs)
  #pragma unroll
  for (int p = 0; p < 2; ++p) {
    int cbase = p*64 + cg*4;
    #pragma unroll
    for (int i2 = 0; i2 < 4; ++i2) {
      f16x4 hv, lv;
      #pragma unroll
      for (int j = 0; j < 4; ++j) {
        float v = (i2 == 0) ? r[p*4+j].x : (i2 == 1) ? r[p*4+j].y
                : (i2 == 2) ? r[p*4+j].z : r[p*4+j].w;
        f16 hq = (f16)v;
        hv[j] = hq;
        lv[j] = (f16)(v - (float)hq);
      }
      *(f16x4*)(FhS + (q*4 + i2)*P2 + cbase) = hv;
      *(f16x4*)(FlS + (q*4 + i2)*P2 + cbase) = lv;
    }
  }

  // ---- W fragments for phase 1 (k 128..255)
  #pragma unroll
  for (int ot = 0; ot < 2; ++ot) {
    const f16* bh  = Wh + (size_t)(orow + ot*16) * CIN + 128 + koff;
    const f16* blp = Wl + (size_t)(orow + ot*16) * CIN + 128 + koff;
    #pragma unroll
    for (int ks = 0; ks < 4; ++ks) {
      wah[ot][ks] = *(const f16x8*)(bh  + ks*32);
      wal[ot][ks] = *(const f16x8*)(blp + ks*32);
    }
  }
  __syncthreads();   // LDS phase 1 ready

  // ---- compute phase 1
  #pragma unroll
  for (int ks = 0; ks < 4; ++ks) {
    #pragma unroll
    for (int pt = 0; pt < 4; ++pt) {
      int rofs = (pt*16 + (l & 15)) * P2 + ks*32 + koff;
      f16x8 bh = *(const f16x8*)(FhS + rofs);
      f16x8 bl = *(const f16x8*)(FlS + rofs);
      #pragma unroll
      for (int ot = 0; ot < 2; ++ot) {
        acc[pt][ot] = __builtin_amdgcn_mfma_f32_16x16x32_f16(wah[ot][ks], bh, acc[pt][ot], 0, 0, 0);
        acc[pt][ot] = __builtin_amdgcn_mfma_f32_16x16x32_f16(wah[ot][ks], bl, acc[pt][ot], 0, 0, 0);
        acc[pt][ot] = __builtin_amdgcn_mfma_f32_16x16x32_f16(wal[ot][ks], bh, acc[pt][ot], 0, 0, 0);
      }
    }
  }

  // ---- per-pixel norm: lane covers 8 o's; xor-16/32 sums this wave's 32 o's
  #pragma unroll
  for (int pt = 0; pt < 4; ++pt) {
    float s = 0.0f;
    #pragma unroll
    for (int ot = 0; ot < 2; ++ot)
      #pragma unroll
      for (int rr = 0; rr < 4; ++rr) s += acc[pt][ot][rr] * acc[pt][ot][rr];
    s += __shfl_xor(s, 16);
    s += __shfl_xor(s, 32);
    if ((l >> 4) == 0) nrm[w][pt*16 + l] = s;
  }
  __syncthreads();

  // ---- normalize + packed fp16 store (8B per store)
  #pragma unroll
  for (int pt = 0; pt < 4; ++pt) {
    int p = pt*16 + (l & 15);
    float n2 = nrm[0][p] + nrm[1][p] + nrm[2][p] + nrm[3][p];
    float invn = 1.0f / fmaxf(sqrtf(n2), 1e-12f);
    size_t rowb = ((size_t)b*NPIX + p0 + p) * CHID + w*32 + (l >> 4) * 4;
    #pragma unroll
    for (int ot = 0; ot < 2; ++ot) {
      f16x4 o4;
      #pragma unroll
      for (int rr = 0; rr < 4; ++rr) o4[rr] = (f16)(acc[pt][ot][rr] * invn);
      *(f16x4*)(sfn + rowb + ot*16) = o4;
    }
  }
}

// Per-(b,n) block. Phase 0: all 256 sample positions -> LDS (packed clamped
// corner coords + pre-validated bilinear weights). Phase 1: wave-half per
// sample, 32 lanes x f16x4 = 128 ch, 8 samples/iter, xor-shuffle reduce.
__global__ __launch_bounds__(256) void kSampleH(
    const f16* __restrict__ sfn, const float* __restrict__ nf,
    const float* __restrict__ node_coords, const float* __restrict__ node_scores,
    const float* __restrict__ node_depths,
    const float* __restrict__ Kl, const float* __restrict__ Rl,
    const float* __restrict__ tinit, const float* __restrict__ Ks,
    const float* __restrict__ Rs, const float* __restrict__ tsat,
    const float* __restrict__ radius, float* __restrict__ logits)
{
  int bnI = blockIdx.x;
  int b = bnI >> 8;
  int tid = threadIdx.x;
  __shared__ uint32_t cpk[SS];     // x0c | x1c<<8 | y0c<<16 | y1c<<24
  __shared__ float4   cwt[SS];     // bilinear weights (0 where invalid)
  __shared__ float    simbuf[SS];

  // ---- phase 0: per-sample projection, coords, weights
  {
    float A[9], ub[3];
    compute_geom(Kl + b*9, Rl + b*9, tinit + b*3, Ks + b*9, Rs + b*9, tsat + b*3,
                 node_coords[bnI*2 + 0], node_coords[bnI*2 + 1], node_depths[bnI],
                 A, ub);
    float rad = radius[b];
    int s = tid;
    int sx = s & 15, sy = s >> 4;
    float oxr = (-1.0f + sx*(2.0f/15.0f)) * rad;
    float oyr = (-1.0f + sy*(2.0f/15.0f)) * rad;
    float cx, cy;
    proj(A, ub, oxr, oyr, cx, cy);
    float px = cx * (256.0f/255.0f) - 0.5f;
    float py = cy * (256.0f/255.0f) - 0.5f;
    float x0f = floorf(px), y0f = floorf(py);
    float wx1 = px - x0f, wy1 = py - y0f;
    float wx0 = 1.0f - wx1, wy0 = 1.0f - wy1;
    int x0 = (int)x0f, y0 = (int)y0f;
    int x1 = x0 + 1, y1 = y0 + 1;
    bool vx0 = (x0 >= 0) && (x0 < WW);
    bool vx1 = (x1 >= 0) && (x1 < WW);
    bool vy0 = (y0 >= 0) && (y0 < HH);
    bool vy1 = (y1 >= 0) && (y1 < HH);
    int x0c = min(max(x0, 0), WW-1), x1c = min(max(x1, 0), WW-1);
    int y0c = min(max(y0, 0), HH-1), y1c = min(max(y1, 0), HH-1);
    cpk[s] = (uint32_t)x0c | ((uint32_t)x1c << 8)
           | ((uint32_t)y0c << 16) | ((uint32_t)y1c << 24);
    float4 wv;
    wv.x = (vx0 && vy0) ? wy0*wx0 : 0.0f;
    wv.y = (vx1 && vy0) ? wy0*wx1 : 0.0f;
    wv.z = (vx0 && vy1) ? wy1*wx0 : 0.0f;
    wv.w = (vx1 && vy1) ? wy1*wx1 : 0.0f;
    cwt[s] = wv;
  }

  // ---- per-lane nf fragment (fp32, full precision)
  const int l    = tid & 63;
  const int w    = tid >> 6;
  const int cg   = l & 31;          // channel group: channels cg*4..cg*4+3
  const int half = l >> 5;          // which sample of this wave's pair
  const int c4   = cg * 4;
  f32x4 nf4 = *(const f32x4*)(nf + (size_t)bnI*CHID + c4);
  const f16* __restrict__ base = sfn + (size_t)b * NPIX * CHID;

  __syncthreads();

  #pragma unroll 4
  for (int it = 0; it < 32; ++it) {
    int s = it*8 + w*2 + half;
    uint32_t pc = cpk[s];
    float4 wt = cwt[s];
    int x0c = pc & 255, x1c = (pc >> 8) & 255;
    int r0 = ((pc >> 16) & 255) << 8;        // y0c*WW
    int r1 = (pc >> 24) << 8;                // y1c*WW
    f16x4 v00 = *(const f16x4*)(base + (((r0 + x0c) << 7) + c4));
    f16x4 v10 = *(const f16x4*)(base + (((r0 + x1c) << 7) + c4));
    f16x4 v01 = *(const f16x4*)(base + (((r1 + x0c) << 7) + c4));
    f16x4 v11 = *(const f16x4*)(base + (((r1 + x1c) << 7) + c4));
    float d00 = nf4[0]*(float)v00[0] + nf4[1]*(float)v00[1]
              + nf4[2]*(float)v00[2] + nf4[3]*(float)v00[3];
    float d10 = nf4[0]*(float)v10[0] + nf4[1]*(float)v10[1]
              + nf4[2]*(float)v10[2] + nf4[3]*(float)v10[3];
    float d01 = nf4[0]*(float)v01[0] + nf4[1]*(float)v01[1]
              + nf4[2]*(float)v01[2] + nf4[3]*(float)v01[3];
    float d11 = nf4[0]*(float)v11[0] + nf4[1]*(float)v11[1]
              + nf4[2]*(float)v11[2] + nf4[3]*(float)v11[3];
    float p = wt.x*d00 + wt.y*d10 + wt.z*d01 + wt.w*d11;
    #pragma unroll
    for (int off = 1; off < 32; off <<= 1) p += __shfl_xor(p, off);
    if (cg == 0) simbuf[s] = p;
  }
  __syncthreads();

  atomicAdd(&logits[b*SS + tid], node_scores[bnI] * simbuf[tid]);
}

// ======================= Path C (zero-workspace fallback) =======================

__global__ __launch_bounds__(256) void kZero(float* stash)
{
  int idx = blockIdx.x * 256 + threadIdx.x;
  if (idx < BB*SS) stash[idx] = 0.0f;
}

// Block per (b,n). On-the-fly sf at 4 corners per sample. Slow but zero-ws.
__global__ __launch_bounds__(256) void kDirectSlow(
    const float* __restrict__ sat, const float* __restrict__ Wsat,
    const float* __restrict__ bsat, const float* __restrict__ feats,
    const float* __restrict__ Wn, const float* __restrict__ bn,
    const float* __restrict__ node_coords, const float* __restrict__ node_scores,
    const float* __restrict__ node_depths,
    const float* __restrict__ Kl, const float* __restrict__ Rl,
    const float* __restrict__ tinit, const float* __restrict__ Ks,
    const float* __restrict__ Rs, const float* __restrict__ tsat,
    const float* __restrict__ radius, float* logitsStash)
{
  __shared__ float frow[CIN];
  __shared__ float nfs[CHID];
  __shared__ float satc[4][CIN];
  __shared__ float sfb[4][256];
  __shared__ float red[8];

  int bnI = blockIdx.x;
  int b = bnI >> 8;
  int tid = threadIdx.x;
  int lane = tid & 63, wv = tid >> 6;

  frow[tid] = feats[(size_t)bnI*CIN + tid];
  __syncthreads();

  {
    float acc = 0.0f;
    if (tid < CHID) {
      acc = bn[tid];
      for (int c = 0; c < CIN; ++c) acc += frow[c] * Wn[c*CHID + tid];
    }
    float s2 = (tid < CHID) ? acc*acc : 0.0f;
    #pragma unroll
    for (int off = 32; off; off >>= 1) s2 += __shfl_down(s2, off);
    if (lane == 0) red[wv] = s2;
    __syncthreads();
    float inv = 1.0f / fmaxf(sqrtf(red[0] + red[1] + red[2] + red[3]), 1e-12f);
    if (tid < CHID) nfs[tid] = acc * inv;
    __syncthreads();
  }

  float A[9], ub[3];
  compute_geom(Kl + b*9, Rl + b*9, tinit + b*3, Ks + b*9, Rs + b*9, tsat + b*3,
               node_coords[bnI*2 + 0], node_coords[bnI*2 + 1], node_depths[bnI],
               A, ub);
  float rad = radius[b];
  float score_n = node_scores[bnI];
  const int h = tid & 127, half = tid >> 7;
  const float* Wrow = Wsat + (size_t)h * CIN + half * 128;

  for (int s = 0; s < SS; ++s) {
    int sx = s & 15, sy = s >> 4;
    float oxr = (-1.0f + sx*(2.0f/15.0f)) * rad;
    float oyr = (-1.0f + sy*(2.0f/15.0f)) * rad;
    float cx, cy;
    proj(A, ub, oxr, oyr, cx, cy);
    float px = cx * (256.0f/255.0f) - 0.5f;
    float py = cy * (256.0f/255.0f) - 0.5f;
    float x0f = floorf(px), y0f = floorf(py);
    float wx1 = px - x0f, wy1 = py - y0f;
    float wx0 = 1.0f - wx1, wy0 = 1.0f - wy1;
    int x0 = (int)x0f, y0 = (int)y0f, x1 = x0 + 1, y1 = y0 + 1;
    int cxs[4] = {x0, x1, x0, x1};
    int cys[4] = {y0, y0, y1, y1};
    float wts[4] = {wy0*wx0, wy0*wx1, wy1*wx0, wy1*wx1};
    #pragma unroll
    for (int j = 0; j < 4; ++j) {
      bool ok = (cxs[j] >= 0) && (cxs[j] < WW) && (cys[j] >= 0) && (cys[j] < HH);
      if (!ok) wts[j] = 0.0f;
      cxs[j] = min(max(cxs[j], 0), WW - 1);
      cys[j] = min(max(cys[j], 0), HH - 1);
    }
    __syncthreads();
    {
      size_t base = (size_t)(b*CIN + tid) * NPIX;
      #pragma unroll
      for (int j = 0; j < 4; ++j)
        satc[j][tid] = sat[base + cys[j]*WW + cxs[j]];
    }
    __syncthreads();
    {
      float a0 = 0.f, a1 = 0.f, a2 = 0.f, a3 = 0.f;
      #pragma unroll 4
      for (int k = 0; k < 128; k += 4) {
        float4 w = *(const float4*)(Wrow + k);
        int kk = half*128 + k;
        a0 += w.x*satc[0][kk] + w.y*satc[0][kk+1] + w.z*satc[0][kk+2] + w.w*satc[0][kk+3];
        a1 += w.x*satc[1][kk] + w.y*satc[1][kk+1] + w.z*satc[1][kk+2] + w.w*satc[1][kk+3];
        a2 += w.x*satc[2][kk] + w.y*satc[2][kk+1] + w.z*satc[2][kk+2] + w.w*satc[2][kk+3];
        a3 += w.x*satc[3][kk] + w.y*satc[3][kk+1] + w.z*satc[3][kk+2] + w.w*satc[3][kk+3];
      }
      sfb[0][tid] = a0; sfb[1][tid] = a1; sfb[2][tid] = a2; sfb[3][tid] = a3;
    }
    __syncthreads();
    float samp = 0.0f;
    #pragma unroll 1
    for (int j = 0; j < 4; ++j) {
      float n2 = 0.0f, nd = 0.0f;
      if (tid < CHID) {
        float sfh = sfb[j][tid] + sfb[j][tid + 128] + bsat[tid];
        n2 = sfh * sfh;
        nd = nfs[tid] * sfh;
      }
      #pragma unroll
      for (int off = 32; off; off >>= 1) {
        n2 += __shfl_down(n2, off);
        nd += __shfl_down(nd, off);
      }
      if (lane == 0) { red[wv*2] = n2; red[wv*2 + 1] = nd; }
      __syncthreads();
      float t1 = red[0] + red[2] + red[4] + red[6];
      float t2 = red[1] + red[3] + red[5] + red[7];
      samp += wts[j] * (t2 / fmaxf(sqrtf(t1), 1e-12f));
      __syncthreads();
    }
    if (tid == 0) atomicAdd(&logitsStash[b*SS + s], score_n * samp);
  }
}

// ================================ epilogue ==================================

// logits may alias the SCORES region of `out` (Path C): thread tid reads
// logits float at index OUT_SCORES+b*SS+tid and later writes scores to the
// exact same float — 1:1 per-thread aliasing, no cross-thread hazard.
__global__ __launch_bounds__(256) void kFinal(
    const float* logits, const float* lscale,
    const float* radius, const float* tinit,
    const float* node_coords, const float* node_depths,
    const float* Kl, const float* Rl,
    const float* Ks, const float* Rs,
    const float* tsat, float* out)
{
  int b = blockIdx.x;
  int tid = threadIdx.x;
  int lane = tid & 63, wv = tid >> 6;
  __shared__ float redm[4], rede[4], av[4];
  __shared__ int ai[4], bestS;

  float scale = expf(lscale[0]);
  float t = logits[b*SS + tid] * scale;

  float m = t;
  #pragma unroll
  for (int off = 32; off; off >>= 1) m = fmaxf(m, __shfl_down(m, off));
  if (lane == 0) redm[wv] = m;
  __syncthreads();
  float M = fmaxf(fmaxf(redm[0], redm[1]), fmaxf(redm[2], redm[3]));

  float e = expf(t - M);
  float se = e;
  #pragma unroll
  for (int off = 32; off; off >>= 1) se += __shfl_down(se, off);
  if (lane == 0) rede[wv] = se;
  __syncthreads();
  float Z = rede[0] + rede[1] + rede[2] + rede[3];

  float vmax = t; int idx = tid;
  #pragma unroll
  for (int off = 32; off; off >>= 1) {
    float ov = __shfl_down(vmax, off);
    int   oi = __shfl_down(idx, off);
    if (ov > vmax || (ov == vmax && oi < idx)) { vmax = ov; idx = oi; }
  }
  if (lane == 0) { av[wv] = vmax; ai[wv] = idx; }
  __syncthreads();
  if (tid == 0) {
    float bv = av[0]; int bi = ai[0];
    #pragma unroll
    for (int w = 1; w < 4; ++w)
      if (av[w] > bv || (av[w] == bv && ai[w] < bi)) { bv = av[w]; bi = ai[w]; }
    bestS = bi;
  }
  __syncthreads();
  int best = bestS;

  out[OUT_SCORES + b*SS + tid] = e / Z;

  float rad = radius[b];
  {
    int sx = tid & 15, sy = tid >> 4;
    float ox = -1.0f + sx*(2.0f/15.0f);
    float oy = -1.0f + sy*(2.0f/15.0f);
    size_t ct = OUT_CANDT + ((size_t)b*SS + tid)*3;
    out[ct + 0] = tinit[b*3 + 0] + ox*rad;
    out[ct + 1] = tinit[b*3 + 1] + oy*rad;
    out[ct + 2] = tinit[b*3 + 2];
  }

  {
    int n = tid;
    int bnI = b*NN + n;
    float A[9], ub[3];
    compute_geom(Kl + b*9, Rl + b*9, tinit + b*3, Ks + b*9, Rs + b*9, tsat + b*3,
                 node_coords[bnI*2 + 0], node_coords[bnI*2 + 1], node_depths[bnI],
                 A, ub);
    int bx = best & 15, by = best >> 4;
    float oxr = (-1.0f + bx*(2.0f/15.0f)) * rad;
    float oyr = (-1.0f + by*(2.0f/15.0f)) * rad;
    float cx, cy;
    proj(A, ub, oxr, oyr, cx, cy);
    out[OUT_MATCH + (size_t)bnI*2 + 0] = cx;
    out[OUT_MATCH + (size_t)bnI*2 + 1] = cy;
    float vl = (cx >= 0.0f && cx < (float)WW && cy >= 0.0f && cy < (float)HH) ? 1.0f : 0.0f;
    out[OUT_VALID + bnI] = vl;
  }
}

extern "C" void kernel_launch(void* const* d_in, const int* in_sizes, int n_in,
                              void* d_out, int out_size, void* d_ws, size_t ws_size,
                              hipStream_t stream)
{
  (void)in_sizes; (void)n_in; (void)out_size;
  const float* node_coords   = (const float*)d_in[0];
  const float* node_scores   = (const float*)d_in[1];
  const float* node_features = (const float*)d_in[2];
  const float* node_depths   = (const float*)d_in[3];
  const float* K_left        = (const float*)d_in[4];
  const float* R_l2w         = (const float*)d_in[5];
  const float* t_init        = (const float*)d_in[6];
  const float* sat           = (const float*)d_in[7];
  const float* K_sat         = (const float*)d_in[8];
  const float* R_sat         = (const float*)d_in[9];
  const float* t_sat         = (const float*)d_in[10];
  const float* radius        = (const float*)d_in[11];
  // d_in[12] = search_steps (int32, 16) — baked in
  const float* W_node        = (const float*)d_in[13];
  const float* b_node        = (const float*)d_in[14];
  const float* W_sat         = (const float*)d_in[15];
  const float* b_sat         = (const float*)d_in[16];
  const float* lscale        = (const float*)d_in[17];

  float* out = (float*)d_out;
  char* ws = (char*)d_ws;

  const size_t sfnB = (size_t)BB * NPIX * CHID * sizeof(f16);   // 32 MiB
  const size_t whB  = (size_t)CIN * CHID * sizeof(f16);         // 64 KiB
  const size_t nfB  = (size_t)BB * NN * CHID * sizeof(float);   // 512 KiB
  const size_t logB = (size_t)BB * SS * sizeof(float);          // 4 KiB
  const size_t needA = sfnB + 2*whB + nfB + logB;

  if (ws_size >= needA) {
    f16*   sfn    = (f16*)ws;
    f16*   Wh     = (f16*)(ws + sfnB);
    f16*   Wl     = (f16*)(ws + sfnB + whB);
    float* nf     = (float*)(ws + sfnB + 2*whB);
    float* logits = (float*)(ws + sfnB + 2*whB + nfB);

    kPrep<<<128, 256, 0, stream>>>(W_sat, Wh, Wl, logits);
    kNode<<<BB*NN, 128, 0, stream>>>(node_features, W_node, b_node, nf);
    kSatM<<<dim3(NPIX/64, BB), 256, 0, stream>>>(sat, Wh, Wl, b_sat, sfn);
    kSampleH<<<BB*NN, 256, 0, stream>>>(sfn, nf, node_coords, node_scores,
        node_depths, K_left, R_l2w, t_init, K_sat, R_sat, t_sat, radius, logits);
    kFinal<<<BB, 256, 0, stream>>>(logits, lscale, radius, t_init, node_coords,
                                   node_depths, K_left, R_l2w, K_sat, R_sat,
                                   t_sat, out);
  } else {
    // zero-workspace fallback: fp32 logits stashed in the SCORES region of out
    float* stash = out + OUT_SCORES;
    kZero<<<4, 256, 0, stream>>>(stash);
    kDirectSlow<<<BB*NN, 256, 0, stream>>>(sat, W_sat, b_sat, node_features,
        W_node, b_node, node_coords, node_scores, node_depths,
        K_left, R_l2w, t_init, K_sat, R_sat, t_sat, radius, stash);
    kFinal<<<BB, 256, 0, stream>>>(stash, lscale, radius, t_init, node_coords,
                                   node_depths, K_left, R_l2w, K_sat, R_sat,
                                   t_sat, out);
  }
}

// Round 4
// 472.241 us; speedup vs baseline: 1.0223x; 1.0223x over previous
//
#include <hip/hip_runtime.h>
#include <stdint.h>

typedef _Float16 f16;
typedef __attribute__((ext_vector_type(8))) _Float16 f16x8;
typedef __attribute__((ext_vector_type(4))) _Float16 f16x4;
typedef __attribute__((ext_vector_type(4))) float    f32x4;

constexpr int BB   = 4;
constexpr int NN   = 256;
constexpr int CIN  = 256;
constexpr int CHID = 128;
constexpr int HH   = 256;
constexpr int WW   = 256;
constexpr int NPIX = HH * WW;
constexpr int SS   = 256;

// Output layout (fp32 elements, concatenated in return order)
constexpr int OUT_MATCH  = 0;      // [B,N,2] = 2048
constexpr int OUT_VALID  = 2048;   // [B,N]   = 1024
constexpr int OUT_CANDT  = 3072;   // [B,S,3] = 3072
constexpr int OUT_SCORES = 6144;   // [B,S]   = 1024

// A = K_sat * R_sat^T, ub = A*(R_l2w*(Kinv*[u,v,1]*d) + t_init - t_sat)
static __device__ __forceinline__ void compute_geom(
    const float* Kl, const float* Rl, const float* ti,
    const float* Ks, const float* Rs, const float* ts,
    float u, float v, float d, float* A, float* ub)
{
  float a = Kl[0], bq = Kl[1], c = Kl[2];
  float dq = Kl[3], e = Kl[4], f = Kl[5];
  float g = Kl[6], h = Kl[7], i = Kl[8];
  float cof00 =  (e*i - f*h), cof01 = -(dq*i - f*g), cof02 =  (dq*h - e*g);
  float cof10 = -(bq*i - c*h), cof11 =  (a*i - c*g), cof12 = -(a*h - bq*g);
  float cof20 =  (bq*f - c*e), cof21 = -(a*f - c*dq), cof22 =  (a*e - bq*dq);
  float det = a*cof00 + bq*cof01 + c*cof02;
  float inv = 1.0f / det;
  float k00 = cof00*inv, k01 = cof10*inv, k02 = cof20*inv;
  float k10 = cof01*inv, k11 = cof11*inv, k12 = cof21*inv;
  float k20 = cof02*inv, k21 = cof12*inv, k22 = cof22*inv;
  float cx = (k00*u + k01*v + k02) * d;
  float cy = (k10*u + k11*v + k12) * d;
  float cz = (k20*u + k21*v + k22) * d;
  float w0 = Rl[0]*cx + Rl[1]*cy + Rl[2]*cz + ti[0] - ts[0];
  float w1 = Rl[3]*cx + Rl[4]*cy + Rl[5]*cz + ti[1] - ts[1];
  float w2 = Rl[6]*cx + Rl[7]*cy + Rl[8]*cz + ti[2] - ts[2];
  #pragma unroll
  for (int r = 0; r < 3; ++r)
    #pragma unroll
    for (int cJ = 0; cJ < 3; ++cJ)
      A[r*3 + cJ] = Ks[r*3+0]*Rs[cJ*3+0] + Ks[r*3+1]*Rs[cJ*3+1] + Ks[r*3+2]*Rs[cJ*3+2];
  ub[0] = A[0]*w0 + A[1]*w1 + A[2]*w2;
  ub[1] = A[3]*w0 + A[4]*w1 + A[5]*w2;
  ub[2] = A[6]*w0 + A[7]*w1 + A[8]*w2;
}

static __device__ __forceinline__ void proj(const float* A, const float* ub,
                                            float oxr, float oyr,
                                            float& cx, float& cy)
{
  float u0 = ub[0] + oxr*A[0] + oyr*A[1];
  float u1 = ub[1] + oxr*A[3] + oyr*A[4];
  float u2 = ub[2] + oxr*A[6] + oyr*A[7];
  cx = u0 / u2;
  cy = u1 / u2;
}

// ============================ Path A (ws >= ~34MiB) ============================

// Split W_sat [128][256] fp32 into hi/lo fp16 (error-compensated MFMA operands).
__global__ __launch_bounds__(256) void kPrep(const float* __restrict__ Wsat,
                                             f16* __restrict__ Wh,
                                             f16* __restrict__ Wl,
                                             float* __restrict__ logits)
{
  int idx = blockIdx.x * 256 + threadIdx.x;      // 0..32767
  float v = Wsat[idx];
  f16 hv = (f16)v;
  Wh[idx] = hv;
  Wl[idx] = (f16)(v - (float)hv);
  if (idx < BB*SS) logits[idx] = 0.0f;
}

__global__ __launch_bounds__(128) void kNode(const float* __restrict__ feats,
                                             const float* __restrict__ Wn,
                                             const float* __restrict__ bn,
                                             float* __restrict__ nf)
{
  int bnI = blockIdx.x;
  int h = threadIdx.x;
  __shared__ float frow[CIN];
  __shared__ float red[2];
  frow[h]       = feats[(size_t)bnI*CIN + h];
  frow[h + 128] = feats[(size_t)bnI*CIN + h + 128];
  __syncthreads();
  float acc = bn[h];
  #pragma unroll 8
  for (int c = 0; c < CIN; ++c) acc += frow[c] * Wn[c*CHID + h];
  float s = acc * acc;
  #pragma unroll
  for (int off = 32; off; off >>= 1) s += __shfl_down(s, off);
  if ((h & 63) == 0) red[h >> 6] = s;
  __syncthreads();
  float inv = 1.0f / fmaxf(sqrtf(red[0] + red[1]), 1e-12f);
  nf[(size_t)bnI*CHID + h] = acc * inv;
}

// sf = W_sat @ featmap + b_sat via split-f16 MFMA (3-term: WhFh + WhFl + WlFh),
// channel-normalized, fp16 [B,HW,128].
// v3: 128-px tile, 4 K-phases of 64 ch, double-buffered LDS (74KB, 2 blk/CU).
// ALL W A-fragments preloaded upfront (inner loop has zero W loads), so the
// only outstanding VMEM during MFMAs is the next phase's sat prefetch —
// no vmcnt false-drain (v2's flaw: W loads issued after the prefetch forced
// vmcnt(0) before the first MFMA, serializing everything).
// Per-accumulator k-order unchanged vs v1/v2 -> bit-identical results.
constexpr int P3   = 72;          // f16 pitch: 64 ch + 8 pad (16B-aligned rows)
constexpr int HALF = 128 * P3;    // one phase buffer (f16 units)

static __device__ __forceinline__ void cvt_write(f16* __restrict__ FhS,
                                                 f16* __restrict__ FlS,
                                                 int bufbase, int q, int cr,
                                                 const float4* r)
{
  #pragma unroll
  for (int i2 = 0; i2 < 4; ++i2) {
    f16x8 hv, lv;
    #pragma unroll
    for (int j = 0; j < 8; ++j) {
      float v = (i2 == 0) ? r[j].x : (i2 == 1) ? r[j].y
              : (i2 == 2) ? r[j].z : r[j].w;
      f16 hq = (f16)v;
      hv[j] = hq;
      lv[j] = (f16)(v - (float)hq);
    }
    *(f16x8*)(FhS + bufbase + (q*4 + i2)*P3 + cr*8) = hv;
    *(f16x8*)(FlS + bufbase + (q*4 + i2)*P3 + cr*8) = lv;
  }
}

__global__ __launch_bounds__(256, 2) void kSatM(
    const float* __restrict__ sat, const f16* __restrict__ Wh,
    const f16* __restrict__ Wl, const float* __restrict__ bsat,
    f16* __restrict__ sfn)
{
  const int b  = blockIdx.y;
  const int p0 = blockIdx.x * 128;
  __shared__ f16 FhS[2 * HALF];       // [phase-parity][px][ch-local] hi
  __shared__ f16 FlS[2 * HALF];       // lo
  __shared__ float nrm[4][128];       // per-wave per-pixel |sf|^2 partials

  const int tid = threadIdx.x;
  const int w   = tid >> 6;
  const int l   = tid & 63;
  const int q   = tid & 31;           // px-quad: pixels q*4 .. q*4+3
  const int cr  = tid >> 5;           // channel octet within phase
  const float* Fb = sat + (size_t)b * CIN * NPIX + p0;

  const int orow = w*32 + (l & 15);
  const int koff = (l >> 4) * 8;

  // ---- all W A-fragments upfront (4 ph x 2 ks x 2 ot, hi & lo): 128 VGPR, L2
  f16x8 wah[4][2][2], wal[4][2][2];
  #pragma unroll
  for (int ph = 0; ph < 4; ++ph)
    #pragma unroll
    for (int ks = 0; ks < 2; ++ks)
      #pragma unroll
      for (int ot = 0; ot < 2; ++ot) {
        wah[ph][ks][ot] = *(const f16x8*)(Wh + (size_t)(orow + ot*16)*CIN + ph*64 + ks*32 + koff);
        wal[ph][ks][ot] = *(const f16x8*)(Wl + (size_t)(orow + ot*16)*CIN + ph*64 + ks*32 + koff);
      }

  // ---- accumulators init = bias (added pre-normalization, as in reference)
  f32x4 acc[8][2];
  {
    int ob = w*32 + (l >> 4) * 4;
    f32x4 b0 = *(const f32x4*)(bsat + ob);
    f32x4 b1 = *(const f32x4*)(bsat + ob + 16);
    #pragma unroll
    for (int pt = 0; pt < 8; ++pt) { acc[pt][0] = b0; acc[pt][1] = b1; }
  }

  float4 rA[8];
  // ---- prologue: sat phase 0 -> regs -> LDS buf0
  #pragma unroll
  for (int j = 0; j < 8; ++j)
    rA[j] = *(const float4*)(Fb + (size_t)(cr*8 + j) * NPIX + q*4);
  cvt_write(FhS, FlS, 0, q, cr, rA);
  __syncthreads();

  // ---- pipelined K-phases
  #pragma unroll
  for (int p = 0; p < 4; ++p) {
    const int rb = (p & 1) * HALF;
    // issue next-phase sat loads; they fly under this phase's 96 MFMAs
    if (p < 3) {
      #pragma unroll
      for (int j = 0; j < 8; ++j)
        rA[j] = *(const float4*)(Fb + (size_t)((p+1)*64 + cr*8 + j) * NPIX + q*4);
    }
    #pragma unroll
    for (int ks = 0; ks < 2; ++ks) {
      #pragma unroll
      for (int pt = 0; pt < 8; ++pt) {
        int rofs = rb + (pt*16 + (l & 15)) * P3 + ks*32 + koff;
        f16x8 bh = *(const f16x8*)(FhS + rofs);
        f16x8 bl = *(const f16x8*)(FlS + rofs);
        #pragma unroll
        for (int ot = 0; ot < 2; ++ot) {
          acc[pt][ot] = __builtin_amdgcn_mfma_f32_16x16x32_f16(wah[p][ks][ot], bh, acc[pt][ot], 0, 0, 0);
          acc[pt][ot] = __builtin_amdgcn_mfma_f32_16x16x32_f16(wah[p][ks][ot], bl, acc[pt][ot], 0, 0, 0);
          acc[pt][ot] = __builtin_amdgcn_mfma_f32_16x16x32_f16(wal[p][ks][ot], bh, acc[pt][ot], 0, 0, 0);
        }
      }
    }
    __syncthreads();                       // all waves done reading buf rb
    if (p < 3) {
      cvt_write(FhS, FlS, ((p+1) & 1) * HALF, q, cr, rA);
      __syncthreads();                     // next buf visible to all waves
    }
  }

  // ---- per-pixel norm: lane covers 8 o's; xor-16/32 sums this wave's 32 o's
  #pragma unroll
  for (int pt = 0; pt < 8; ++pt) {
    float s = 0.0f;
    #pragma unroll
    for (int ot = 0; ot < 2; ++ot)
      #pragma unroll
      for (int rr = 0; rr < 4; ++rr) s += acc[pt][ot][rr] * acc[pt][ot][rr];
    s += __shfl_xor(s, 16);
    s += __shfl_xor(s, 32);
    if ((l >> 4) == 0) nrm[w][pt*16 + l] = s;
  }
  __syncthreads();

  // ---- normalize + packed fp16 store (8B per store)
  #pragma unroll
  for (int pt = 0; pt < 8; ++pt) {
    int p = pt*16 + (l & 15);
    float n2 = nrm[0][p] + nrm[1][p] + nrm[2][p] + nrm[3][p];
    float invn = 1.0f / fmaxf(sqrtf(n2), 1e-12f);
    size_t rowb = ((size_t)b*NPIX + p0 + p) * CHID + w*32 + (l >> 4) * 4;
    #pragma unroll
    for (int ot = 0; ot < 2; ++ot) {
      f16x4 o4;
      #pragma unroll
      for (int rr = 0; rr < 4; ++rr) o4[rr] = (f16)(acc[pt][ot][rr] * invn);
      *(f16x4*)(sfn + rowb + ot*16) = o4;
    }
  }
}

// Per-(b,n) block. Phase 0: all 256 sample positions -> LDS (packed clamped
// corner coords + pre-validated bilinear weights). Phase 1: wave-half per
// sample, 32 lanes x f16x4 = 128 ch, 8 samples/iter, xor-shuffle reduce.
__global__ __launch_bounds__(256) void kSampleH(
    const f16* __restrict__ sfn, const float* __restrict__ nf,
    const float* __restrict__ node_coords, const float* __restrict__ node_scores,
    const float* __restrict__ node_depths,
    const float* __restrict__ Kl, const float* __restrict__ Rl,
    const float* __restrict__ tinit, const float* __restrict__ Ks,
    const float* __restrict__ Rs, const float* __restrict__ tsat,
    const float* __restrict__ radius, float* __restrict__ logits)
{
  int bnI = blockIdx.x;
  int b = bnI >> 8;
  int tid = threadIdx.x;
  __shared__ uint32_t cpk[SS];     // x0c | x1c<<8 | y0c<<16 | y1c<<24
  __shared__ float4   cwt[SS];     // bilinear weights (0 where invalid)
  __shared__ float    simbuf[SS];

  // ---- phase 0: per-sample projection, coords, weights
  {
    float A[9], ub[3];
    compute_geom(Kl + b*9, Rl + b*9, tinit + b*3, Ks + b*9, Rs + b*9, tsat + b*3,
                 node_coords[bnI*2 + 0], node_coords[bnI*2 + 1], node_depths[bnI],
                 A, ub);
    float rad = radius[b];
    int s = tid;
    int sx = s & 15, sy = s >> 4;
    float oxr = (-1.0f + sx*(2.0f/15.0f)) * rad;
    float oyr = (-1.0f + sy*(2.0f/15.0f)) * rad;
    float cx, cy;
    proj(A, ub, oxr, oyr, cx, cy);
    float px = cx * (256.0f/255.0f) - 0.5f;
    float py = cy * (256.0f/255.0f) - 0.5f;
    float x0f = floorf(px), y0f = floorf(py);
    float wx1 = px - x0f, wy1 = py - y0f;
    float wx0 = 1.0f - wx1, wy0 = 1.0f - wy1;
    int x0 = (int)x0f, y0 = (int)y0f;
    int x1 = x0 + 1, y1 = y0 + 1;
    bool vx0 = (x0 >= 0) && (x0 < WW);
    bool vx1 = (x1 >= 0) && (x1 < WW);
    bool vy0 = (y0 >= 0) && (y0 < HH);
    bool vy1 = (y1 >= 0) && (y1 < HH);
    int x0c = min(max(x0, 0), WW-1), x1c = min(max(x1, 0), WW-1);
    int y0c = min(max(y0, 0), HH-1), y1c = min(max(y1, 0), HH-1);
    cpk[s] = (uint32_t)x0c | ((uint32_t)x1c << 8)
           | ((uint32_t)y0c << 16) | ((uint32_t)y1c << 24);
    float4 wv;
    wv.x = (vx0 && vy0) ? wy0*wx0 : 0.0f;
    wv.y = (vx1 && vy0) ? wy0*wx1 : 0.0f;
    wv.z = (vx0 && vy1) ? wy1*wx0 : 0.0f;
    wv.w = (vx1 && vy1) ? wy1*wx1 : 0.0f;
    cwt[s] = wv;
  }

  // ---- per-lane nf fragment (fp32, full precision)
  const int l    = tid & 63;
  const int w    = tid >> 6;
  const int cg   = l & 31;          // channel group: channels cg*4..cg*4+3
  const int half = l >> 5;          // which sample of this wave's pair
  const int c4   = cg * 4;
  f32x4 nf4 = *(const f32x4*)(nf + (size_t)bnI*CHID + c4);
  const f16* __restrict__ base = sfn + (size_t)b * NPIX * CHID;

  __syncthreads();

  #pragma unroll 4
  for (int it = 0; it < 32; ++it) {
    int s = it*8 + w*2 + half;
    uint32_t pc = cpk[s];
    float4 wt = cwt[s];
    int x0c = pc & 255, x1c = (pc >> 8) & 255;
    int r0 = ((pc >> 16) & 255) << 8;        // y0c*WW
    int r1 = (pc >> 24) << 8;                // y1c*WW
    f16x4 v00 = *(const f16x4*)(base + (((r0 + x0c) << 7) + c4));
    f16x4 v10 = *(const f16x4*)(base + (((r0 + x1c) << 7) + c4));
    f16x4 v01 = *(const f16x4*)(base + (((r1 + x0c) << 7) + c4));
    f16x4 v11 = *(const f16x4*)(base + (((r1 + x1c) << 7) + c4));
    float d00 = nf4[0]*(float)v00[0] + nf4[1]*(float)v00[1]
              + nf4[2]*(float)v00[2] + nf4[3]*(float)v00[3];
    float d10 = nf4[0]*(float)v10[0] + nf4[1]*(float)v10[1]
              + nf4[2]*(float)v10[2] + nf4[3]*(float)v10[3];
    float d01 = nf4[0]*(float)v01[0] + nf4[1]*(float)v01[1]
              + nf4[2]*(float)v01[2] + nf4[3]*(float)v01[3];
    float d11 = nf4[0]*(float)v11[0] + nf4[1]*(float)v11[1]
              + nf4[2]*(float)v11[2] + nf4[3]*(float)v11[3];
    float p = wt.x*d00 + wt.y*d10 + wt.z*d01 + wt.w*d11;
    #pragma unroll
    for (int off = 1; off < 32; off <<= 1) p += __shfl_xor(p, off);
    if (cg == 0) simbuf[s] = p;
  }
  __syncthreads();

  atomicAdd(&logits[b*SS + tid], node_scores[bnI] * simbuf[tid]);
}

// ======================= Path C (zero-workspace fallback) =======================

__global__ __launch_bounds__(256) void kZero(float* stash)
{
  int idx = blockIdx.x * 256 + threadIdx.x;
  if (idx < BB*SS) stash[idx] = 0.0f;
}

// Block per (b,n). On-the-fly sf at 4 corners per sample. Slow but zero-ws.
__global__ __launch_bounds__(256) void kDirectSlow(
    const float* __restrict__ sat, const float* __restrict__ Wsat,
    const float* __restrict__ bsat, const float* __restrict__ feats,
    const float* __restrict__ Wn, const float* __restrict__ bn,
    const float* __restrict__ node_coords, const float* __restrict__ node_scores,
    const float* __restrict__ node_depths,
    const float* __restrict__ Kl, const float* __restrict__ Rl,
    const float* __restrict__ tinit, const float* __restrict__ Ks,
    const float* __restrict__ Rs, const float* __restrict__ tsat,
    const float* __restrict__ radius, float* logitsStash)
{
  __shared__ float frow[CIN];
  __shared__ float nfs[CHID];
  __shared__ float satc[4][CIN];
  __shared__ float sfb[4][256];
  __shared__ float red[8];

  int bnI = blockIdx.x;
  int b = bnI >> 8;
  int tid = threadIdx.x;
  int lane = tid & 63, wv = tid >> 6;

  frow[tid] = feats[(size_t)bnI*CIN + tid];
  __syncthreads();

  {
    float acc = 0.0f;
    if (tid < CHID) {
      acc = bn[tid];
      for (int c = 0; c < CIN; ++c) acc += frow[c] * Wn[c*CHID + tid];
    }
    float s2 = (tid < CHID) ? acc*acc : 0.0f;
    #pragma unroll
    for (int off = 32; off; off >>= 1) s2 += __shfl_down(s2, off);
    if (lane == 0) red[wv] = s2;
    __syncthreads();
    float inv = 1.0f / fmaxf(sqrtf(red[0] + red[1] + red[2] + red[3]), 1e-12f);
    if (tid < CHID) nfs[tid] = acc * inv;
    __syncthreads();
  }

  float A[9], ub[3];
  compute_geom(Kl + b*9, Rl + b*9, tinit + b*3, Ks + b*9, Rs + b*9, tsat + b*3,
               node_coords[bnI*2 + 0], node_coords[bnI*2 + 1], node_depths[bnI],
               A, ub);
  float rad = radius[b];
  float score_n = node_scores[bnI];
  const int h = tid & 127, half = tid >> 7;
  const float* Wrow = Wsat + (size_t)h * CIN + half * 128;

  for (int s = 0; s < SS; ++s) {
    int sx = s & 15, sy = s >> 4;
    float oxr = (-1.0f + sx*(2.0f/15.0f)) * rad;
    float oyr = (-1.0f + sy*(2.0f/15.0f)) * rad;
    float cx, cy;
    proj(A, ub, oxr, oyr, cx, cy);
    float px = cx * (256.0f/255.0f) - 0.5f;
    float py = cy * (256.0f/255.0f) - 0.5f;
    float x0f = floorf(px), y0f = floorf(py);
    float wx1 = px - x0f, wy1 = py - y0f;
    float wx0 = 1.0f - wx1, wy0 = 1.0f - wy1;
    int x0 = (int)x0f, y0 = (int)y0f, x1 = x0 + 1, y1 = y0 + 1;
    int cxs[4] = {x0, x1, x0, x1};
    int cys[4] = {y0, y0, y1, y1};
    float wts[4] = {wy0*wx0, wy0*wx1, wy1*wx0, wy1*wx1};
    #pragma unroll
    for (int j = 0; j < 4; ++j) {
      bool ok = (cxs[j] >= 0) && (cxs[j] < WW) && (cys[j] >= 0) && (cys[j] < HH);
      if (!ok) wts[j] = 0.0f;
      cxs[j] = min(max(cxs[j], 0), WW - 1);
      cys[j] = min(max(cys[j], 0), HH - 1);
    }
    __syncthreads();
    {
      size_t base = (size_t)(b*CIN + tid) * NPIX;
      #pragma unroll
      for (int j = 0; j < 4; ++j)
        satc[j][tid] = sat[base + cys[j]*WW + cxs[j]];
    }
    __syncthreads();
    {
      float a0 = 0.f, a1 = 0.f, a2 = 0.f, a3 = 0.f;
      #pragma unroll 4
      for (int k = 0; k < 128; k += 4) {
        float4 w = *(const float4*)(Wrow + k);
        int kk = half*128 + k;
        a0 += w.x*satc[0][kk] + w.y*satc[0][kk+1] + w.z*satc[0][kk+2] + w.w*satc[0][kk+3];
        a1 += w.x*satc[1][kk] + w.y*satc[1][kk+1] + w.z*satc[1][kk+2] + w.w*satc[1][kk+3];
        a2 += w.x*satc[2][kk] + w.y*satc[2][kk+1] + w.z*satc[2][kk+2] + w.w*satc[2][kk+3];
        a3 += w.x*satc[3][kk] + w.y*satc[3][kk+1] + w.z*satc[3][kk+2] + w.w*satc[3][kk+3];
      }
      sfb[0][tid] = a0; sfb[1][tid] = a1; sfb[2][tid] = a2; sfb[3][tid] = a3;
    }
    __syncthreads();
    float samp = 0.0f;
    #pragma unroll 1
    for (int j = 0; j < 4; ++j) {
      float n2 = 0.0f, nd = 0.0f;
      if (tid < CHID) {
        float sfh = sfb[j][tid] + sfb[j][tid + 128] + bsat[tid];
        n2 = sfh * sfh;
        nd = nfs[tid] * sfh;
      }
      #pragma unroll
      for (int off = 32; off; off >>= 1) {
        n2 += __shfl_down(n2, off);
        nd += __shfl_down(nd, off);
      }
      if (lane == 0) { red[wv*2] = n2; red[wv*2 + 1] = nd; }
      __syncthreads();
      float t1 = red[0] + red[2] + red[4] + red[6];
      float t2 = red[1] + red[3] + red[5] + red[7];
      samp += wts[j] * (t2 / fmaxf(sqrtf(t1), 1e-12f));
      __syncthreads();
    }
    if (tid == 0) atomicAdd(&logitsStash[b*SS + s], score_n * samp);
  }
}

// ================================ epilogue ==================================

// logits may alias the SCORES region of `out` (Path C): thread tid reads
// logits float at index OUT_SCORES+b*SS+tid and later writes scores to the
// exact same float — 1:1 per-thread aliasing, no cross-thread hazard.
__global__ __launch_bounds__(256) void kFinal(
    const float* logits, const float* lscale,
    const float* radius, const float* tinit,
    const float* node_coords, const float* node_depths,
    const float* Kl, const float* Rl,
    const float* Ks, const float* Rs,
    const float* tsat, float* out)
{
  int b = blockIdx.x;
  int tid = threadIdx.x;
  int lane = tid & 63, wv = tid >> 6;
  __shared__ float redm[4], rede[4], av[4];
  __shared__ int ai[4], bestS;

  float scale = expf(lscale[0]);
  float t = logits[b*SS + tid] * scale;

  float m = t;
  #pragma unroll
  for (int off = 32; off; off >>= 1) m = fmaxf(m, __shfl_down(m, off));
  if (lane == 0) redm[wv] = m;
  __syncthreads();
  float M = fmaxf(fmaxf(redm[0], redm[1]), fmaxf(redm[2], redm[3]));

  float e = expf(t - M);
  float se = e;
  #pragma unroll
  for (int off = 32; off; off >>= 1) se += __shfl_down(se, off);
  if (lane == 0) rede[wv] = se;
  __syncthreads();
  float Z = rede[0] + rede[1] + rede[2] + rede[3];

  float vmax = t; int idx = tid;
  #pragma unroll
  for (int off = 32; off; off >>= 1) {
    float ov = __shfl_down(vmax, off);
    int   oi = __shfl_down(idx, off);
    if (ov > vmax || (ov == vmax && oi < idx)) { vmax = ov; idx = oi; }
  }
  if (lane == 0) { av[wv] = vmax; ai[wv] = idx; }
  __syncthreads();
  if (tid == 0) {
    float bv = av[0]; int bi = ai[0];
    #pragma unroll
    for (int w = 1; w < 4; ++w)
      if (av[w] > bv || (av[w] == bv && ai[w] < bi)) { bv = av[w]; bi = ai[w]; }
    bestS = bi;
  }
  __syncthreads();
  int best = bestS;

  out[OUT_SCORES + b*SS + tid] = e / Z;

  float rad = radius[b];
  {
    int sx = tid & 15, sy = tid >> 4;
    float ox = -1.0f + sx*(2.0f/15.0f);
    float oy = -1.0f + sy*(2.0f/15.0f);
    size_t ct = OUT_CANDT + ((size_t)b*SS + tid)*3;
    out[ct + 0] = tinit[b*3 + 0] + ox*rad;
    out[ct + 1] = tinit[b*3 + 1] + oy*rad;
    out[ct + 2] = tinit[b*3 + 2];
  }

  {
    int n = tid;
    int bnI = b*NN + n;
    float A[9], ub[3];
    compute_geom(Kl + b*9, Rl + b*9, tinit + b*3, Ks + b*9, Rs + b*9, tsat + b*3,
                 node_coords[bnI*2 + 0], node_coords[bnI*2 + 1], node_depths[bnI],
                 A, ub);
    int bx = best & 15, by = best >> 4;
    float oxr = (-1.0f + bx*(2.0f/15.0f)) * rad;
    float oyr = (-1.0f + by*(2.0f/15.0f)) * rad;
    float cx, cy;
    proj(A, ub, oxr, oyr, cx, cy);
    out[OUT_MATCH + (size_t)bnI*2 + 0] = cx;
    out[OUT_MATCH + (size_t)bnI*2 + 1] = cy;
    float vl = (cx >= 0.0f && cx < (float)WW && cy >= 0.0f && cy < (float)HH) ? 1.0f : 0.0f;
    out[OUT_VALID + bnI] = vl;
  }
}

extern "C" void kernel_launch(void* const* d_in, const int* in_sizes, int n_in,
                              void* d_out, int out_size, void* d_ws, size_t ws_size,
                              hipStream_t stream)
{
  (void)in_sizes; (void)n_in; (void)out_size;
  const float* node_coords   = (const float*)d_in[0];
  const float* node_scores   = (const float*)d_in[1];
  const float* node_features = (const float*)d_in[2];
  const float* node_depths   = (const float*)d_in[3];
  const float* K_left        = (const float*)d_in[4];
  const float* R_l2w         = (const float*)d_in[5];
  const float* t_init        = (const float*)d_in[6];
  const float* sat           = (const float*)d_in[7];
  const float* K_sat         = (const float*)d_in[8];
  const float* R_sat         = (const float*)d_in[9];
  const float* t_sat         = (const float*)d_in[10];
  const float* radius        = (const float*)d_in[11];
  // d_in[12] = search_steps (int32, 16) — baked in
  const float* W_node        = (const float*)d_in[13];
  const float* b_node        = (const float*)d_in[14];
  const float* W_sat         = (const float*)d_in[15];
  const float* b_sat         = (const float*)d_in[16];
  const float* lscale        = (const float*)d_in[17];

  float* out = (float*)d_out;
  char* ws = (char*)d_ws;

  const size_t sfnB = (size_t)BB * NPIX * CHID * sizeof(f16);   // 32 MiB
  const size_t whB  = (size_t)CIN * CHID * sizeof(f16);         // 64 KiB
  const size_t nfB  = (size_t)BB * NN * CHID * sizeof(float);   // 512 KiB
  const size_t logB = (size_t)BB * SS * sizeof(float);          // 4 KiB
  const size_t needA = sfnB + 2*whB + nfB + logB;

  if (ws_size >= needA) {
    f16*   sfn    = (f16*)ws;
    f16*   Wh     = (f16*)(ws + sfnB);
    f16*   Wl     = (f16*)(ws + sfnB + whB);
    float* nf     = (float*)(ws + sfnB + 2*whB);
    float* logits = (float*)(ws + sfnB + 2*whB + nfB);

    kPrep<<<128, 256, 0, stream>>>(W_sat, Wh, Wl, logits);
    kNode<<<BB*NN, 128, 0, stream>>>(node_features, W_node, b_node, nf);
    kSatM<<<dim3(NPIX/128, BB), 256, 0, stream>>>(sat, Wh, Wl, b_sat, sfn);
    kSampleH<<<BB*NN, 256, 0, stream>>>(sfn, nf, node_coords, node_scores,
        node_depths, K_left, R_l2w, t_init, K_sat, R_sat, t_sat, radius, logits);
    kFinal<<<BB, 256, 0, stream>>>(logits, lscale, radius, t_init, node_coords,
                                   node_depths, K_left, R_l2w, K_sat, R_sat,
                                   t_sat, out);
  } else {
    // zero-workspace fallback: fp32 logits stashed in the SCORES region of out
    float* stash = out + OUT_SCORES;
    kZero<<<4, 256, 0, stream>>>(stash);
    kDirectSlow<<<BB*NN, 256, 0, stream>>>(sat, W_sat, b_sat, node_features,
        W_node, b_node, node_coords, node_scores, node_depths,
        K_left, R_l2w, t_init, K_sat, R_sat, t_sat, radius, stash);
    kFinal<<<BB, 256, 0, stream>>>(stash, lscale, radius, t_init, node_coords,
                                   node_depths, K_left, R_l2w, K_sat, R_sat,
                                   t_sat, out);
  }
}

// Round 5
// 470.128 us; speedup vs baseline: 1.0269x; 1.0045x over previous
//
#include <hip/hip_runtime.h>
#include <stdint.h>

typedef _Float16 f16;
typedef __attribute__((ext_vector_type(8))) _Float16 f16x8;
typedef __attribute__((ext_vector_type(4))) _Float16 f16x4;
typedef __attribute__((ext_vector_type(4))) float    f32x4;

constexpr int BB   = 4;
constexpr int NN   = 256;
constexpr int CIN  = 256;
constexpr int CHID = 128;
constexpr int HH   = 256;
constexpr int WW   = 256;
constexpr int NPIX = HH * WW;
constexpr int SS   = 256;

// Output layout (fp32 elements, concatenated in return order)
constexpr int OUT_MATCH  = 0;      // [B,N,2] = 2048
constexpr int OUT_VALID  = 2048;   // [B,N]   = 1024
constexpr int OUT_CANDT  = 3072;   // [B,S,3] = 3072
constexpr int OUT_SCORES = 6144;   // [B,S]   = 1024

// A = K_sat * R_sat^T, ub = A*(R_l2w*(Kinv*[u,v,1]*d) + t_init - t_sat)
static __device__ __forceinline__ void compute_geom(
    const float* Kl, const float* Rl, const float* ti,
    const float* Ks, const float* Rs, const float* ts,
    float u, float v, float d, float* A, float* ub)
{
  float a = Kl[0], bq = Kl[1], c = Kl[2];
  float dq = Kl[3], e = Kl[4], f = Kl[5];
  float g = Kl[6], h = Kl[7], i = Kl[8];
  float cof00 =  (e*i - f*h), cof01 = -(dq*i - f*g), cof02 =  (dq*h - e*g);
  float cof10 = -(bq*i - c*h), cof11 =  (a*i - c*g), cof12 = -(a*h - bq*g);
  float cof20 =  (bq*f - c*e), cof21 = -(a*f - c*dq), cof22 =  (a*e - bq*dq);
  float det = a*cof00 + bq*cof01 + c*cof02;
  float inv = 1.0f / det;
  float k00 = cof00*inv, k01 = cof10*inv, k02 = cof20*inv;
  float k10 = cof01*inv, k11 = cof11*inv, k12 = cof21*inv;
  float k20 = cof02*inv, k21 = cof12*inv, k22 = cof22*inv;
  float cx = (k00*u + k01*v + k02) * d;
  float cy = (k10*u + k11*v + k12) * d;
  float cz = (k20*u + k21*v + k22) * d;
  float w0 = Rl[0]*cx + Rl[1]*cy + Rl[2]*cz + ti[0] - ts[0];
  float w1 = Rl[3]*cx + Rl[4]*cy + Rl[5]*cz + ti[1] - ts[1];
  float w2 = Rl[6]*cx + Rl[7]*cy + Rl[8]*cz + ti[2] - ts[2];
  #pragma unroll
  for (int r = 0; r < 3; ++r)
    #pragma unroll
    for (int cJ = 0; cJ < 3; ++cJ)
      A[r*3 + cJ] = Ks[r*3+0]*Rs[cJ*3+0] + Ks[r*3+1]*Rs[cJ*3+1] + Ks[r*3+2]*Rs[cJ*3+2];
  ub[0] = A[0]*w0 + A[1]*w1 + A[2]*w2;
  ub[1] = A[3]*w0 + A[4]*w1 + A[5]*w2;
  ub[2] = A[6]*w0 + A[7]*w1 + A[8]*w2;
}

static __device__ __forceinline__ void proj(const float* A, const float* ub,
                                            float oxr, float oyr,
                                            float& cx, float& cy)
{
  float u0 = ub[0] + oxr*A[0] + oyr*A[1];
  float u1 = ub[1] + oxr*A[3] + oyr*A[4];
  float u2 = ub[2] + oxr*A[6] + oyr*A[7];
  cx = u0 / u2;
  cy = u1 / u2;
}

// ============================ Path A (ws >= ~34MiB) ============================

// Split W_sat [128][256] fp32 into hi/lo fp16 (error-compensated MFMA operands).
__global__ __launch_bounds__(256) void kPrep(const float* __restrict__ Wsat,
                                             f16* __restrict__ Wh,
                                             f16* __restrict__ Wl,
                                             float* __restrict__ logits)
{
  int idx = blockIdx.x * 256 + threadIdx.x;      // 0..32767
  float v = Wsat[idx];
  f16 hv = (f16)v;
  Wh[idx] = hv;
  Wl[idx] = (f16)(v - (float)hv);
  if (idx < BB*SS) logits[idx] = 0.0f;
}

__global__ __launch_bounds__(128) void kNode(const float* __restrict__ feats,
                                             const float* __restrict__ Wn,
                                             const float* __restrict__ bn,
                                             float* __restrict__ nf)
{
  int bnI = blockIdx.x;
  int h = threadIdx.x;
  __shared__ float frow[CIN];
  __shared__ float red[2];
  frow[h]       = feats[(size_t)bnI*CIN + h];
  frow[h + 128] = feats[(size_t)bnI*CIN + h + 128];
  __syncthreads();
  float acc = bn[h];
  #pragma unroll 8
  for (int c = 0; c < CIN; ++c) acc += frow[c] * Wn[c*CHID + h];
  float s = acc * acc;
  #pragma unroll
  for (int off = 32; off; off >>= 1) s += __shfl_down(s, off);
  if ((h & 63) == 0) red[h >> 6] = s;
  __syncthreads();
  float inv = 1.0f / fmaxf(sqrtf(red[0] + red[1]), 1e-12f);
  nf[(size_t)bnI*CHID + h] = acc * inv;
}

// sf = W_sat @ featmap + b_sat via split-f16 MFMA (3-term: WhFh + WhFl + WlFh),
// channel-normalized, fp16 [B,HW,128].
// v4: = v3 + T2 XOR-swizzle on the F LDS tiles. v1/v2/v3 all had an 8-way
// bank conflict on every fragment ds_read_b128 (bank = 4*((row+colgrp)%8)
// for all three pitches) — the inner loop was LDS-serialization-bound, which
// is why pipelining (v2/v3) was neutral. Fix: pitch = exactly 128 B and swap
// 16-B granules by granule ^= (px&7) on BOTH write and read (attn-verified
// recipe, +89% there). Accumulation order unchanged -> bit-identical output.
constexpr int P3   = 64;          // f16 pitch: 64 ch = 128 B exactly (swizzled)
constexpr int HALF = 128 * P3;    // one phase buffer (f16 units) = 16 KB

static __device__ __forceinline__ void cvt_write(f16* __restrict__ FhS,
                                                 f16* __restrict__ FlS,
                                                 int bufbase, int q, int cr,
                                                 const float4* r)
{
  #pragma unroll
  for (int i2 = 0; i2 < 4; ++i2) {
    int px  = q*4 + i2;
    int col = (cr ^ (px & 7)) * 8;       // swizzled 16-B granule
    f16x8 hv, lv;
    #pragma unroll
    for (int j = 0; j < 8; ++j) {
      float v = (i2 == 0) ? r[j].x : (i2 == 1) ? r[j].y
              : (i2 == 2) ? r[j].z : r[j].w;
      f16 hq = (f16)v;
      hv[j] = hq;
      lv[j] = (f16)(v - (float)hq);
    }
    *(f16x8*)(FhS + bufbase + px*P3 + col) = hv;
    *(f16x8*)(FlS + bufbase + px*P3 + col) = lv;
  }
}

__global__ __launch_bounds__(256, 2) void kSatM(
    const float* __restrict__ sat, const f16* __restrict__ Wh,
    const f16* __restrict__ Wl, const float* __restrict__ bsat,
    f16* __restrict__ sfn)
{
  const int b  = blockIdx.y;
  const int p0 = blockIdx.x * 128;
  __shared__ f16 FhS[2 * HALF];       // [phase-parity][px][ch-local swz] hi
  __shared__ f16 FlS[2 * HALF];       // lo
  __shared__ float nrm[4][128];       // per-wave per-pixel |sf|^2 partials

  const int tid = threadIdx.x;
  const int w   = tid >> 6;
  const int l   = tid & 63;
  const int q   = tid & 31;           // px-quad: pixels q*4 .. q*4+3
  const int cr  = tid >> 5;           // channel octet within phase
  const float* Fb = sat + (size_t)b * CIN * NPIX + p0;

  const int orow = w*32 + (l & 15);
  const int koff = (l >> 4) * 8;

  // ---- all W A-fragments upfront (4 ph x 2 ks x 2 ot, hi & lo): 128 VGPR, L2
  f16x8 wah[4][2][2], wal[4][2][2];
  #pragma unroll
  for (int ph = 0; ph < 4; ++ph)
    #pragma unroll
    for (int ks = 0; ks < 2; ++ks)
      #pragma unroll
      for (int ot = 0; ot < 2; ++ot) {
        wah[ph][ks][ot] = *(const f16x8*)(Wh + (size_t)(orow + ot*16)*CIN + ph*64 + ks*32 + koff);
        wal[ph][ks][ot] = *(const f16x8*)(Wl + (size_t)(orow + ot*16)*CIN + ph*64 + ks*32 + koff);
      }

  // ---- accumulators init = bias (added pre-normalization, as in reference)
  f32x4 acc[8][2];
  {
    int ob = w*32 + (l >> 4) * 4;
    f32x4 b0 = *(const f32x4*)(bsat + ob);
    f32x4 b1 = *(const f32x4*)(bsat + ob + 16);
    #pragma unroll
    for (int pt = 0; pt < 8; ++pt) { acc[pt][0] = b0; acc[pt][1] = b1; }
  }

  float4 rA[8];
  // ---- prologue: sat phase 0 -> regs -> LDS buf0
  #pragma unroll
  for (int j = 0; j < 8; ++j)
    rA[j] = *(const float4*)(Fb + (size_t)(cr*8 + j) * NPIX + q*4);
  cvt_write(FhS, FlS, 0, q, cr, rA);
  __syncthreads();

  // ---- pipelined K-phases
  #pragma unroll
  for (int p = 0; p < 4; ++p) {
    const int rb = (p & 1) * HALF;
    // issue next-phase sat loads; they fly under this phase's 96 MFMAs
    if (p < 3) {
      #pragma unroll
      for (int j = 0; j < 8; ++j)
        rA[j] = *(const float4*)(Fb + (size_t)((p+1)*64 + cr*8 + j) * NPIX + q*4);
    }
    #pragma unroll
    for (int ks = 0; ks < 2; ++ks) {
      #pragma unroll
      for (int pt = 0; pt < 8; ++pt) {
        int px   = pt*16 + (l & 15);
        int gr   = ((ks*4 + (l >> 4)) ^ (l & 7)) * 8;   // swizzled granule
        int rofs = rb + px*P3 + gr;
        f16x8 bh = *(const f16x8*)(FhS + rofs);
        f16x8 bl = *(const f16x8*)(FlS + rofs);
        #pragma unroll
        for (int ot = 0; ot < 2; ++ot) {
          acc[pt][ot] = __builtin_amdgcn_mfma_f32_16x16x32_f16(wah[p][ks][ot], bh, acc[pt][ot], 0, 0, 0);
          acc[pt][ot] = __builtin_amdgcn_mfma_f32_16x16x32_f16(wah[p][ks][ot], bl, acc[pt][ot], 0, 0, 0);
          acc[pt][ot] = __builtin_amdgcn_mfma_f32_16x16x32_f16(wal[p][ks][ot], bh, acc[pt][ot], 0, 0, 0);
        }
      }
    }
    __syncthreads();                       // all waves done reading buf rb
    if (p < 3) {
      cvt_write(FhS, FlS, ((p+1) & 1) * HALF, q, cr, rA);
      __syncthreads();                     // next buf visible to all waves
    }
  }

  // ---- per-pixel norm: lane covers 8 o's; xor-16/32 sums this wave's 32 o's
  #pragma unroll
  for (int pt = 0; pt < 8; ++pt) {
    float s = 0.0f;
    #pragma unroll
    for (int ot = 0; ot < 2; ++ot)
      #pragma unroll
      for (int rr = 0; rr < 4; ++rr) s += acc[pt][ot][rr] * acc[pt][ot][rr];
    s += __shfl_xor(s, 16);
    s += __shfl_xor(s, 32);
    if ((l >> 4) == 0) nrm[w][pt*16 + l] = s;
  }
  __syncthreads();

  // ---- normalize + packed fp16 store (8B per store)
  #pragma unroll
  for (int pt = 0; pt < 8; ++pt) {
    int p = pt*16 + (l & 15);
    float n2 = nrm[0][p] + nrm[1][p] + nrm[2][p] + nrm[3][p];
    float invn = 1.0f / fmaxf(sqrtf(n2), 1e-12f);
    size_t rowb = ((size_t)b*NPIX + p0 + p) * CHID + w*32 + (l >> 4) * 4;
    #pragma unroll
    for (int ot = 0; ot < 2; ++ot) {
      f16x4 o4;
      #pragma unroll
      for (int rr = 0; rr < 4; ++rr) o4[rr] = (f16)(acc[pt][ot][rr] * invn);
      *(f16x4*)(sfn + rowb + ot*16) = o4;
    }
  }
}

// Per-(b,n) block. Phase 0: all 256 sample positions -> LDS (packed clamped
// corner coords + pre-validated bilinear weights). Phase 1: wave-half per
// sample, 32 lanes x f16x4 = 128 ch, 8 samples/iter, xor-shuffle reduce.
__global__ __launch_bounds__(256) void kSampleH(
    const f16* __restrict__ sfn, const float* __restrict__ nf,
    const float* __restrict__ node_coords, const float* __restrict__ node_scores,
    const float* __restrict__ node_depths,
    const float* __restrict__ Kl, const float* __restrict__ Rl,
    const float* __restrict__ tinit, const float* __restrict__ Ks,
    const float* __restrict__ Rs, const float* __restrict__ tsat,
    const float* __restrict__ radius, float* __restrict__ logits)
{
  int bnI = blockIdx.x;
  int b = bnI >> 8;
  int tid = threadIdx.x;
  __shared__ uint32_t cpk[SS];     // x0c | x1c<<8 | y0c<<16 | y1c<<24
  __shared__ float4   cwt[SS];     // bilinear weights (0 where invalid)
  __shared__ float    simbuf[SS];

  // ---- phase 0: per-sample projection, coords, weights
  {
    float A[9], ub[3];
    compute_geom(Kl + b*9, Rl + b*9, tinit + b*3, Ks + b*9, Rs + b*9, tsat + b*3,
                 node_coords[bnI*2 + 0], node_coords[bnI*2 + 1], node_depths[bnI],
                 A, ub);
    float rad = radius[b];
    int s = tid;
    int sx = s & 15, sy = s >> 4;
    float oxr = (-1.0f + sx*(2.0f/15.0f)) * rad;
    float oyr = (-1.0f + sy*(2.0f/15.0f)) * rad;
    float cx, cy;
    proj(A, ub, oxr, oyr, cx, cy);
    float px = cx * (256.0f/255.0f) - 0.5f;
    float py = cy * (256.0f/255.0f) - 0.5f;
    float x0f = floorf(px), y0f = floorf(py);
    float wx1 = px - x0f, wy1 = py - y0f;
    float wx0 = 1.0f - wx1, wy0 = 1.0f - wy1;
    int x0 = (int)x0f, y0 = (int)y0f;
    int x1 = x0 + 1, y1 = y0 + 1;
    bool vx0 = (x0 >= 0) && (x0 < WW);
    bool vx1 = (x1 >= 0) && (x1 < WW);
    bool vy0 = (y0 >= 0) && (y0 < HH);
    bool vy1 = (y1 >= 0) && (y1 < HH);
    int x0c = min(max(x0, 0), WW-1), x1c = min(max(x1, 0), WW-1);
    int y0c = min(max(y0, 0), HH-1), y1c = min(max(y1, 0), HH-1);
    cpk[s] = (uint32_t)x0c | ((uint32_t)x1c << 8)
           | ((uint32_t)y0c << 16) | ((uint32_t)y1c << 24);
    float4 wv;
    wv.x = (vx0 && vy0) ? wy0*wx0 : 0.0f;
    wv.y = (vx1 && vy0) ? wy0*wx1 : 0.0f;
    wv.z = (vx0 && vy1) ? wy1*wx0 : 0.0f;
    wv.w = (vx1 && vy1) ? wy1*wx1 : 0.0f;
    cwt[s] = wv;
  }

  // ---- per-lane nf fragment (fp32, full precision)
  const int l    = tid & 63;
  const int w    = tid >> 6;
  const int cg   = l & 31;          // channel group: channels cg*4..cg*4+3
  const int half = l >> 5;          // which sample of this wave's pair
  const int c4   = cg * 4;
  f32x4 nf4 = *(const f32x4*)(nf + (size_t)bnI*CHID + c4);
  const f16* __restrict__ base = sfn + (size_t)b * NPIX * CHID;

  __syncthreads();

  #pragma unroll 4
  for (int it = 0; it < 32; ++it) {
    int s = it*8 + w*2 + half;
    uint32_t pc = cpk[s];
    float4 wt = cwt[s];
    int x0c = pc & 255, x1c = (pc >> 8) & 255;
    int r0 = ((pc >> 16) & 255) << 8;        // y0c*WW
    int r1 = (pc >> 24) << 8;                // y1c*WW
    f16x4 v00 = *(const f16x4*)(base + (((r0 + x0c) << 7) + c4));
    f16x4 v10 = *(const f16x4*)(base + (((r0 + x1c) << 7) + c4));
    f16x4 v01 = *(const f16x4*)(base + (((r1 + x0c) << 7) + c4));
    f16x4 v11 = *(const f16x4*)(base + (((r1 + x1c) << 7) + c4));
    float d00 = nf4[0]*(float)v00[0] + nf4[1]*(float)v00[1]
              + nf4[2]*(float)v00[2] + nf4[3]*(float)v00[3];
    float d10 = nf4[0]*(float)v10[0] + nf4[1]*(float)v10[1]
              + nf4[2]*(float)v10[2] + nf4[3]*(float)v10[3];
    float d01 = nf4[0]*(float)v01[0] + nf4[1]*(float)v01[1]
              + nf4[2]*(float)v01[2] + nf4[3]*(float)v01[3];
    float d11 = nf4[0]*(float)v11[0] + nf4[1]*(float)v11[1]
              + nf4[2]*(float)v11[2] + nf4[3]*(float)v11[3];
    float p = wt.x*d00 + wt.y*d10 + wt.z*d01 + wt.w*d11;
    #pragma unroll
    for (int off = 1; off < 32; off <<= 1) p += __shfl_xor(p, off);
    if (cg == 0) simbuf[s] = p;
  }
  __syncthreads();

  atomicAdd(&logits[b*SS + tid], node_scores[bnI] * simbuf[tid]);
}

// ======================= Path C (zero-workspace fallback) =======================

__global__ __launch_bounds__(256) void kZero(float* stash)
{
  int idx = blockIdx.x * 256 + threadIdx.x;
  if (idx < BB*SS) stash[idx] = 0.0f;
}

// Block per (b,n). On-the-fly sf at 4 corners per sample. Slow but zero-ws.
__global__ __launch_bounds__(256) void kDirectSlow(
    const float* __restrict__ sat, const float* __restrict__ Wsat,
    const float* __restrict__ bsat, const float* __restrict__ feats,
    const float* __restrict__ Wn, const float* __restrict__ bn,
    const float* __restrict__ node_coords, const float* __restrict__ node_scores,
    const float* __restrict__ node_depths,
    const float* __restrict__ Kl, const float* __restrict__ Rl,
    const float* __restrict__ tinit, const float* __restrict__ Ks,
    const float* __restrict__ Rs, const float* __restrict__ tsat,
    const float* __restrict__ radius, float* logitsStash)
{
  __shared__ float frow[CIN];
  __shared__ float nfs[CHID];
  __shared__ float satc[4][CIN];
  __shared__ float sfb[4][256];
  __shared__ float red[8];

  int bnI = blockIdx.x;
  int b = bnI >> 8;
  int tid = threadIdx.x;
  int lane = tid & 63, wv = tid >> 6;

  frow[tid] = feats[(size_t)bnI*CIN + tid];
  __syncthreads();

  {
    float acc = 0.0f;
    if (tid < CHID) {
      acc = bn[tid];
      for (int c = 0; c < CIN; ++c) acc += frow[c] * Wn[c*CHID + tid];
    }
    float s2 = (tid < CHID) ? acc*acc : 0.0f;
    #pragma unroll
    for (int off = 32; off; off >>= 1) s2 += __shfl_down(s2, off);
    if (lane == 0) red[wv] = s2;
    __syncthreads();
    float inv = 1.0f / fmaxf(sqrtf(red[0] + red[1] + red[2] + red[3]), 1e-12f);
    if (tid < CHID) nfs[tid] = acc * inv;
    __syncthreads();
  }

  float A[9], ub[3];
  compute_geom(Kl + b*9, Rl + b*9, tinit + b*3, Ks + b*9, Rs + b*9, tsat + b*3,
               node_coords[bnI*2 + 0], node_coords[bnI*2 + 1], node_depths[bnI],
               A, ub);
  float rad = radius[b];
  float score_n = node_scores[bnI];
  const int h = tid & 127, half = tid >> 7;
  const float* Wrow = Wsat + (size_t)h * CIN + half * 128;

  for (int s = 0; s < SS; ++s) {
    int sx = s & 15, sy = s >> 4;
    float oxr = (-1.0f + sx*(2.0f/15.0f)) * rad;
    float oyr = (-1.0f + sy*(2.0f/15.0f)) * rad;
    float cx, cy;
    proj(A, ub, oxr, oyr, cx, cy);
    float px = cx * (256.0f/255.0f) - 0.5f;
    float py = cy * (256.0f/255.0f) - 0.5f;
    float x0f = floorf(px), y0f = floorf(py);
    float wx1 = px - x0f, wy1 = py - y0f;
    float wx0 = 1.0f - wx1, wy0 = 1.0f - wy1;
    int x0 = (int)x0f, y0 = (int)y0f, x1 = x0 + 1, y1 = y0 + 1;
    int cxs[4] = {x0, x1, x0, x1};
    int cys[4] = {y0, y0, y1, y1};
    float wts[4] = {wy0*wx0, wy0*wx1, wy1*wx0, wy1*wx1};
    #pragma unroll
    for (int j = 0; j < 4; ++j) {
      bool ok = (cxs[j] >= 0) && (cxs[j] < WW) && (cys[j] >= 0) && (cys[j] < HH);
      if (!ok) wts[j] = 0.0f;
      cxs[j] = min(max(cxs[j], 0), WW - 1);
      cys[j] = min(max(cys[j], 0), HH - 1);
    }
    __syncthreads();
    {
      size_t base = (size_t)(b*CIN + tid) * NPIX;
      #pragma unroll
      for (int j = 0; j < 4; ++j)
        satc[j][tid] = sat[base + cys[j]*WW + cxs[j]];
    }
    __syncthreads();
    {
      float a0 = 0.f, a1 = 0.f, a2 = 0.f, a3 = 0.f;
      #pragma unroll 4
      for (int k = 0; k < 128; k += 4) {
        float4 w = *(const float4*)(Wrow + k);
        int kk = half*128 + k;
        a0 += w.x*satc[0][kk] + w.y*satc[0][kk+1] + w.z*satc[0][kk+2] + w.w*satc[0][kk+3];
        a1 += w.x*satc[1][kk] + w.y*satc[1][kk+1] + w.z*satc[1][kk+2] + w.w*satc[1][kk+3];
        a2 += w.x*satc[2][kk] + w.y*satc[2][kk+1] + w.z*satc[2][kk+2] + w.w*satc[2][kk+3];
        a3 += w.x*satc[3][kk] + w.y*satc[3][kk+1] + w.z*satc[3][kk+2] + w.w*satc[3][kk+3];
      }
      sfb[0][tid] = a0; sfb[1][tid] = a1; sfb[2][tid] = a2; sfb[3][tid] = a3;
    }
    __syncthreads();
    float samp = 0.0f;
    #pragma unroll 1
    for (int j = 0; j < 4; ++j) {
      float n2 = 0.0f, nd = 0.0f;
      if (tid < CHID) {
        float sfh = sfb[j][tid] + sfb[j][tid + 128] + bsat[tid];
        n2 = sfh * sfh;
        nd = nfs[tid] * sfh;
      }
      #pragma unroll
      for (int off = 32; off; off >>= 1) {
        n2 += __shfl_down(n2, off);
        nd += __shfl_down(nd, off);
      }
      if (lane == 0) { red[wv*2] = n2; red[wv*2 + 1] = nd; }
      __syncthreads();
      float t1 = red[0] + red[2] + red[4] + red[6];
      float t2 = red[1] + red[3] + red[5] + red[7];
      samp += wts[j] * (t2 / fmaxf(sqrtf(t1), 1e-12f));
      __syncthreads();
    }
    if (tid == 0) atomicAdd(&logitsStash[b*SS + s], score_n * samp);
  }
}

// ================================ epilogue ==================================

// logits may alias the SCORES region of `out` (Path C): thread tid reads
// logits float at index OUT_SCORES+b*SS+tid and later writes scores to the
// exact same float — 1:1 per-thread aliasing, no cross-thread hazard.
__global__ __launch_bounds__(256) void kFinal(
    const float* logits, const float* lscale,
    const float* radius, const float* tinit,
    const float* node_coords, const float* node_depths,
    const float* Kl, const float* Rl,
    const float* Ks, const float* Rs,
    const float* tsat, float* out)
{
  int b = blockIdx.x;
  int tid = threadIdx.x;
  int lane = tid & 63, wv = tid >> 6;
  __shared__ float redm[4], rede[4], av[4];
  __shared__ int ai[4], bestS;

  float scale = expf(lscale[0]);
  float t = logits[b*SS + tid] * scale;

  float m = t;
  #pragma unroll
  for (int off = 32; off; off >>= 1) m = fmaxf(m, __shfl_down(m, off));
  if (lane == 0) redm[wv] = m;
  __syncthreads();
  float M = fmaxf(fmaxf(redm[0], redm[1]), fmaxf(redm[2], redm[3]));

  float e = expf(t - M);
  float se = e;
  #pragma unroll
  for (int off = 32; off; off >>= 1) se += __shfl_down(se, off);
  if (lane == 0) rede[wv] = se;
  __syncthreads();
  float Z = rede[0] + rede[1] + rede[2] + rede[3];

  float vmax = t; int idx = tid;
  #pragma unroll
  for (int off = 32; off; off >>= 1) {
    float ov = __shfl_down(vmax, off);
    int   oi = __shfl_down(idx, off);
    if (ov > vmax || (ov == vmax && oi < idx)) { vmax = ov; idx = oi; }
  }
  if (lane == 0) { av[wv] = vmax; ai[wv] = idx; }
  __syncthreads();
  if (tid == 0) {
    float bv = av[0]; int bi = ai[0];
    #pragma unroll
    for (int w = 1; w < 4; ++w)
      if (av[w] > bv || (av[w] == bv && ai[w] < bi)) { bv = av[w]; bi = ai[w]; }
    bestS = bi;
  }
  __syncthreads();
  int best = bestS;

  out[OUT_SCORES + b*SS + tid] = e / Z;

  float rad = radius[b];
  {
    int sx = tid & 15, sy = tid >> 4;
    float ox = -1.0f + sx*(2.0f/15.0f);
    float oy = -1.0f + sy*(2.0f/15.0f);
    size_t ct = OUT_CANDT + ((size_t)b*SS + tid)*3;
    out[ct + 0] = tinit[b*3 + 0] + ox*rad;
    out[ct + 1] = tinit[b*3 + 1] + oy*rad;
    out[ct + 2] = tinit[b*3 + 2];
  }

  {
    int n = tid;
    int bnI = b*NN + n;
    float A[9], ub[3];
    compute_geom(Kl + b*9, Rl + b*9, tinit + b*3, Ks + b*9, Rs + b*9, tsat + b*3,
                 node_coords[bnI*2 + 0], node_coords[bnI*2 + 1], node_depths[bnI],
                 A, ub);
    int bx = best & 15, by = best >> 4;
    float oxr = (-1.0f + bx*(2.0f/15.0f)) * rad;
    float oyr = (-1.0f + by*(2.0f/15.0f)) * rad;
    float cx, cy;
    proj(A, ub, oxr, oyr, cx, cy);
    out[OUT_MATCH + (size_t)bnI*2 + 0] = cx;
    out[OUT_MATCH + (size_t)bnI*2 + 1] = cy;
    float vl = (cx >= 0.0f && cx < (float)WW && cy >= 0.0f && cy < (float)HH) ? 1.0f : 0.0f;
    out[OUT_VALID + bnI] = vl;
  }
}

extern "C" void kernel_launch(void* const* d_in, const int* in_sizes, int n_in,
                              void* d_out, int out_size, void* d_ws, size_t ws_size,
                              hipStream_t stream)
{
  (void)in_sizes; (void)n_in; (void)out_size;
  const float* node_coords   = (const float*)d_in[0];
  const float* node_scores   = (const float*)d_in[1];
  const float* node_features = (const float*)d_in[2];
  const float* node_depths   = (const float*)d_in[3];
  const float* K_left        = (const float*)d_in[4];
  const float* R_l2w         = (const float*)d_in[5];
  const float* t_init        = (const float*)d_in[6];
  const float* sat           = (const float*)d_in[7];
  const float* K_sat         = (const float*)d_in[8];
  const float* R_sat         = (const float*)d_in[9];
  const float* t_sat         = (const float*)d_in[10];
  const float* radius        = (const float*)d_in[11];
  // d_in[12] = search_steps (int32, 16) — baked in
  const float* W_node        = (const float*)d_in[13];
  const float* b_node        = (const float*)d_in[14];
  const float* W_sat         = (const float*)d_in[15];
  const float* b_sat         = (const float*)d_in[16];
  const float* lscale        = (const float*)d_in[17];

  float* out = (float*)d_out;
  char* ws = (char*)d_ws;

  const size_t sfnB = (size_t)BB * NPIX * CHID * sizeof(f16);   // 32 MiB
  const size_t whB  = (size_t)CIN * CHID * sizeof(f16);         // 64 KiB
  const size_t nfB  = (size_t)BB * NN * CHID * sizeof(float);   // 512 KiB
  const size_t logB = (size_t)BB * SS * sizeof(float);          // 4 KiB
  const size_t needA = sfnB + 2*whB + nfB + logB;

  if (ws_size >= needA) {
    f16*   sfn    = (f16*)ws;
    f16*   Wh     = (f16*)(ws + sfnB);
    f16*   Wl     = (f16*)(ws + sfnB + whB);
    float* nf     = (float*)(ws + sfnB + 2*whB);
    float* logits = (float*)(ws + sfnB + 2*whB + nfB);

    kPrep<<<128, 256, 0, stream>>>(W_sat, Wh, Wl, logits);
    kNode<<<BB*NN, 128, 0, stream>>>(node_features, W_node, b_node, nf);
    kSatM<<<dim3(NPIX/128, BB), 256, 0, stream>>>(sat, Wh, Wl, b_sat, sfn);
    kSampleH<<<BB*NN, 256, 0, stream>>>(sfn, nf, node_coords, node_scores,
        node_depths, K_left, R_l2w, t_init, K_sat, R_sat, t_sat, radius, logits);
    kFinal<<<BB, 256, 0, stream>>>(logits, lscale, radius, t_init, node_coords,
                                   node_depths, K_left, R_l2w, K_sat, R_sat,
                                   t_sat, out);
  } else {
    // zero-workspace fallback: fp32 logits stashed in the SCORES region of out
    float* stash = out + OUT_SCORES;
    kZero<<<4, 256, 0, stream>>>(stash);
    kDirectSlow<<<BB*NN, 256, 0, stream>>>(sat, W_sat, b_sat, node_features,
        W_node, b_node, node_coords, node_scores, node_depths,
        K_left, R_l2w, t_init, K_sat, R_sat, t_sat, radius, stash);
    kFinal<<<BB, 256, 0, stream>>>(stash, lscale, radius, t_init, node_coords,
                                   node_depths, K_left, R_l2w, K_sat, R_sat,
                                   t_sat, out);
  }
}